// Round 1
// baseline (607.917 us; speedup 1.0000x reference)
//
#include <hip/hip_runtime.h>

#define TOK   65536      // B*N tokens
#define DIMS  256        // D
#define NCODE 2048       // K codebook
#define LOSSOFF 16777216
#define IDXOFF  16777217

typedef _Float16 f16x8 __attribute__((ext_vector_type(8)));
typedef float    f32x4 __attribute__((ext_vector_type(4)));

// ---------- async global->LDS, 16B per lane ----------
__device__ __forceinline__ void ld16(void* lds, const void* g) {
  __builtin_amdgcn_global_load_lds(
      (const __attribute__((address_space(1))) unsigned int*)g,
      (__attribute__((address_space(3))) unsigned int*)lds, 16, 0, 0);
}

// ---------- K0a: transpose embed [D][K] -> embedT [K][D] fp32 + fp16 hi/lo planes
__global__ void k_prep(const float* __restrict__ embed, float* __restrict__ embedT,
                       _Float16* __restrict__ eTh, _Float16* __restrict__ eTl) {
  __shared__ float t[32][33];
  int tx = threadIdx.x & 31, ty = threadIdx.x >> 5;
  int k0 = blockIdx.x * 32, d0 = blockIdx.y * 32;
#pragma unroll
  for (int i = 0; i < 4; ++i) {
    int d = ty + i * 8;
    t[tx][d] = embed[(size_t)(d0 + d) * NCODE + k0 + tx]; // t[k_local][d_local]
  }
  __syncthreads();
#pragma unroll
  for (int i = 0; i < 4; ++i) {
    int kl = ty + i * 8;
    float v = t[kl][tx];
    size_t o = (size_t)(k0 + kl) * DIMS + d0 + tx;
    embedT[o] = v;
    _Float16 h = (_Float16)v;
    eTh[o] = h;
    eTl[o] = (_Float16)(v - (float)h);
  }
}

// ---------- K0b: e2[k] = sum_d embed[d][k]^2 (fp64 accumulate) ----------
__global__ void k_e2(const float* __restrict__ embed, float* __restrict__ e2) {
  int k = blockIdx.x * 256 + threadIdx.x;
  double a = 0.0;
  for (int d = 0; d < DIMS; ++d) {
    float v = embed[(size_t)d * NCODE + k];
    a += (double)v * (double)v;
  }
  e2[k] = (float)a;
}

// ---------- K1: score GEMM (hi/lo fp16 split) + per-wave argmin partials ----------
__global__ __launch_bounds__(256, 2) void k_score(
    const float* __restrict__ x, const _Float16* __restrict__ eTh,
    const _Float16* __restrict__ eTl, const float* __restrict__ e2,
    unsigned long long* __restrict__ part) {
  __shared__ float    Al[2][128 * 32];   // fp32 A tile, XOR-swizzled 16B granules
  __shared__ _Float16 Bh[2][128 * 32];   // fp16 hi plane, linear
  __shared__ _Float16 Bl[2][128 * 32];   // fp16 lo plane, linear

  int tid = threadIdx.x, lane = tid & 63, wid = tid >> 6;
  int wm = wid >> 1, wn = wid & 1;
  int bid = blockIdx.x;
  int wg = (bid & 7) * 1024 + (bid >> 3);   // XCD-bijective swizzle (8192 = 8*1024)
  int mblk = wg >> 4, nblk = wg & 15;
  int t0 = mblk * 128, c0 = nblk * 128;
  int col = lane & 15;

  float e2n[4];
#pragma unroll
  for (int n = 0; n < 4; ++n) e2n[n] = e2[c0 + wn * 64 + n * 16 + col];

  f32x4 acc[4][4] = {};

  auto stage = [&](int ck, int buf) {
    int kb = ck * 32;
    // A: 128 rows x 32 fp32 = 16 issues; source pre-swizzled so linear LDS dest
    // yields granule slot (g ^ (row&7)) — read side applies the same XOR.
#pragma unroll
    for (int q = 0; q < 4; ++q) {
      int i = wid * 4 + q;
      int row = i * 8 + (lane >> 3);
      int gl = (lane & 7) ^ (lane >> 3);
      ld16(&Al[buf][i * 256], &x[(size_t)(t0 + row) * DIMS + kb + gl * 4]);
    }
    // B: 128 rows x 32 fp16 per plane = 8 issues each, linear
#pragma unroll
    for (int q = 0; q < 2; ++q) {
      int j = wid * 2 + q;
      int row = j * 16 + (lane >> 2);
      size_t src = (size_t)(c0 + row) * DIMS + kb + (lane & 3) * 8;
      ld16(&Bh[buf][j * 512], &eTh[src]);
      ld16(&Bl[buf][j * 512], &eTl[src]);
    }
  };

  stage(0, 0);
  __syncthreads();

  for (int c = 0; c < 8; ++c) {
    int buf = c & 1;
    if (c < 7) stage(c + 1, buf ^ 1);

    int ko = (lane >> 4) * 8;  // k offset within 32
    f16x8 ah[4], al[4], bh[4], bl[4];
#pragma unroll
    for (int m = 0; m < 4; ++m) {
      int row = wm * 64 + m * 16 + col;
      int sw = row & 7;
      int g0 = ((ko >> 2)) ^ sw;
      int g1 = ((ko >> 2) + 1) ^ sw;
      f32x4 f0 = *(const f32x4*)&Al[buf][row * 32 + g0 * 4];
      f32x4 f1 = *(const f32x4*)&Al[buf][row * 32 + g1 * 4];
#pragma unroll
      for (int e = 0; e < 4; ++e) {
        _Float16 h = (_Float16)f0[e];
        ah[m][e] = h; al[m][e] = (_Float16)(f0[e] - (float)h);
        _Float16 h2 = (_Float16)f1[e];
        ah[m][e + 4] = h2; al[m][e + 4] = (_Float16)(f1[e] - (float)h2);
      }
    }
#pragma unroll
    for (int n = 0; n < 4; ++n) {
      int row = wn * 64 + n * 16 + col;
      bh[n] = *(const f16x8*)&Bh[buf][row * 32 + ko];
      bl[n] = *(const f16x8*)&Bl[buf][row * 32 + ko];
    }
#pragma unroll
    for (int m = 0; m < 4; ++m)
#pragma unroll
      for (int n = 0; n < 4; ++n) {
        acc[m][n] = __builtin_amdgcn_mfma_f32_16x16x32_f16(ah[m], bh[n], acc[m][n], 0, 0, 0);
        acc[m][n] = __builtin_amdgcn_mfma_f32_16x16x32_f16(ah[m], bl[n], acc[m][n], 0, 0, 0);
        acc[m][n] = __builtin_amdgcn_mfma_f32_16x16x32_f16(al[m], bh[n], acc[m][n], 0, 0, 0);
      }
    __syncthreads();
  }

  // epilogue: s = e2 - 2*dot; u64 sortable key (low bits = code -> argmin-first ties)
  int g = lane >> 4;
#pragma unroll
  for (int m = 0; m < 4; ++m)
#pragma unroll
    for (int r = 0; r < 4; ++r) {
      unsigned long long best = ~0ull;
#pragma unroll
      for (int n = 0; n < 4; ++n) {
        float s = e2n[n] - 2.0f * acc[m][n][r];
        unsigned u = __float_as_uint(s);
        u ^= (u & 0x80000000u) ? 0xFFFFFFFFu : 0x80000000u;
        unsigned long long key = ((unsigned long long)u << 32) |
                                 (unsigned)(c0 + wn * 64 + n * 16 + col);
        if (key < best) best = key;
      }
      for (int off = 1; off < 16; off <<= 1) {
        unsigned long long o = __shfl_xor(best, off, 64);
        if (o < best) best = o;
      }
      if (col == 0) {
        int token = t0 + wm * 64 + m * 16 + g * 4 + r;
        part[(size_t)token * 32 + nblk * 2 + wn] = best;
      }
    }
}

// ---------- K2: reduce 32 partials/token -> index; zero loss slot ----------
__global__ void k_argmin(const unsigned long long* __restrict__ part,
                         float* __restrict__ out, int* __restrict__ idxw) {
  int token = blockIdx.x * 256 + threadIdx.x;
  unsigned long long best = ~0ull;
#pragma unroll 8
  for (int i = 0; i < 32; ++i) {
    unsigned long long v = part[(size_t)token * 32 + i];
    if (v < best) best = v;
  }
  unsigned code = (unsigned)(best & 0xFFFFFFFFull);
  out[IDXOFF + token] = (float)code;
  idxw[token] = (int)code;
  if (token == 0) out[LOSSOFF] = 0.0f;
}

// ---------- K3: gather codes, STE output, commitment loss ----------
__global__ void k_gather(const float* __restrict__ x, const float* __restrict__ embedT,
                         const int* __restrict__ idxw, float* __restrict__ out) {
  int gid = blockIdx.x * 256 + threadIdx.x;
  int token = gid >> 6;
  int dp = (gid & 63) * 4;
  int code = idxw[token];
  f32x4 q  = *(const f32x4*)&embedT[(size_t)code * DIMS + dp];
  f32x4 xv = *(const f32x4*)&x[(size_t)token * DIMS + dp];
  f32x4 dff = q - xv;                       // mimic ref: out = x + (q - x)
  f32x4 o = xv + dff;
  *(f32x4*)&out[(size_t)token * DIMS + dp] = o;
  float s = dff[0] * dff[0] + dff[1] * dff[1] + dff[2] * dff[2] + dff[3] * dff[3];
  for (int off = 32; off; off >>= 1) s += __shfl_xor(s, off, 64);
  __shared__ float red[4];
  int lane = threadIdx.x & 63, wid = threadIdx.x >> 6;
  if (lane == 0) red[wid] = s;
  __syncthreads();
  if (threadIdx.x == 0) {
    float tsum = (red[0] + red[1] + red[2] + red[3]) * (0.25f / 16777216.0f);
    atomicAdd(&out[LOSSOFF], tsum);
  }
}

extern "C" void kernel_launch(void* const* d_in, const int* in_sizes, int n_in,
                              void* d_out, int out_size, void* d_ws, size_t ws_size,
                              hipStream_t stream) {
  const float* x     = (const float*)d_in[0];
  const float* embed = (const float*)d_in[1];
  float* out = (float*)d_out;
  char* w = (char*)d_ws;
  _Float16* eTh   = (_Float16*)w;                       // 1 MB
  _Float16* eTl   = (_Float16*)(w + (1u << 20));        // 1 MB
  float*    embedT= (float*)(w + (2u << 20));           // 2 MB
  float*    e2    = (float*)(w + (4u << 20));           // 8 KB
  int*      idxw  = (int*)(w + (4u << 20) + (1u << 16));// 256 KB
  // argmin partials live in the quantize region of d_out (overwritten by k_gather later)
  unsigned long long* part = (unsigned long long*)d_out;

  hipLaunchKernelGGL(k_prep,   dim3(NCODE / 32, DIMS / 32), dim3(256), 0, stream, embed, embedT, eTh, eTl);
  hipLaunchKernelGGL(k_e2,     dim3(NCODE / 256),           dim3(256), 0, stream, embed, e2);
  hipLaunchKernelGGL(k_score,  dim3(8192),                  dim3(256), 0, stream, x, eTh, eTl, e2, part);
  hipLaunchKernelGGL(k_argmin, dim3(TOK / 256),             dim3(256), 0, stream, part, out, idxw);
  hipLaunchKernelGGL(k_gather, dim3(TOK * DIMS / 4 / 256),  dim3(256), 0, stream, x, embedT, idxw, out);
}

// Round 3
// 518.047 us; speedup vs baseline: 1.1735x; 1.1735x over previous
//
#include <hip/hip_runtime.h>

#define TOK   65536      // B*N tokens
#define DIMS  256        // D
#define NCODE 2048       // K codebook
#define LOSSOFF 16777216
#define IDXOFF  16777217

typedef _Float16 f16x8 __attribute__((ext_vector_type(8)));
typedef _Float16 f16x4 __attribute__((ext_vector_type(4)));
typedef float    f32x4 __attribute__((ext_vector_type(4)));

__device__ __forceinline__ void ld16(void* lds, const void* g) {
  __builtin_amdgcn_global_load_lds(
      (const __attribute__((address_space(1))) unsigned int*)g,
      (__attribute__((address_space(3))) unsigned int*)lds, 16, 0, 0);
}

__device__ __forceinline__ unsigned long long umin64(unsigned long long a,
                                                     unsigned long long b) {
  return a < b ? a : b;
}

// ---------- K0a: transpose embed [D][K] -> embedT [K][D] fp32 + fp16 hi/lo planes
__global__ void k_prep(const float* __restrict__ embed, float* __restrict__ embedT,
                       _Float16* __restrict__ eTh, _Float16* __restrict__ eTl) {
  __shared__ float t[32][33];
  int tx = threadIdx.x & 31, ty = threadIdx.x >> 5;
  int k0 = blockIdx.x * 32, d0 = blockIdx.y * 32;
#pragma unroll
  for (int i = 0; i < 4; ++i) {
    int d = ty + i * 8;
    t[tx][d] = embed[(size_t)(d0 + d) * NCODE + k0 + tx];
  }
  __syncthreads();
#pragma unroll
  for (int i = 0; i < 4; ++i) {
    int kl = ty + i * 8;
    float v = t[kl][tx];
    size_t o = (size_t)(k0 + kl) * DIMS + d0 + tx;
    embedT[o] = v;
    _Float16 h = (_Float16)v;
    eTh[o] = h;
    eTl[o] = (_Float16)(v - (float)h);
  }
}

// ---------- K0b: e2[k] = sum_d embed[d][k]^2 (fp64 accumulate) ----------
__global__ void k_e2(const float* __restrict__ embed, float* __restrict__ e2) {
  int k = blockIdx.x * 256 + threadIdx.x;
  double a = 0.0;
  for (int d = 0; d < DIMS; ++d) {
    float v = embed[(size_t)d * NCODE + k];
    a += (double)v * (double)v;
  }
  e2[k] = (float)a;
}

// ---------- K0c: split x -> fp16 hi/lo planes (coalesced, memory-bound) ----------
__global__ void k_xsplit(const float* __restrict__ x, _Float16* __restrict__ xh,
                         _Float16* __restrict__ xl) {
  size_t base = (size_t)(blockIdx.x * 256 + threadIdx.x);
#pragma unroll
  for (int i = 0; i < 8; ++i) {
    size_t o = (base + (size_t)i * 524288) * 4;
    f32x4 v = *(const f32x4*)&x[o];
    f16x4 h, l;
#pragma unroll
    for (int e = 0; e < 4; ++e) {
      h[e] = (_Float16)v[e];
      l[e] = (_Float16)(v[e] - (float)h[e]);
    }
    *(f16x4*)&xh[o] = h;
    *(f16x4*)&xl[o] = l;
  }
}

// ---------- K0d: init per-token argmin cells + loss slot ----------
__global__ void k_init(unsigned long long* __restrict__ part, float* __restrict__ out) {
  int i = blockIdx.x * 256 + threadIdx.x;
  part[i] = ~0ull;
  if (i == 0) out[LOSSOFF] = 0.0f;
}

// ---------- K1: score GEMM (pre-split fp16 planes, swizzled LDS) + atomicMin argmin
__global__ __launch_bounds__(256, 2) void k_score(
    const _Float16* __restrict__ xh, const _Float16* __restrict__ xl,
    const _Float16* __restrict__ eTh, const _Float16* __restrict__ eTl,
    const float* __restrict__ e2, unsigned long long* __restrict__ part) {
  // 4 planes x 2 bufs x [128 rows][32 fp16] = 64 KiB
  // LDS swizzle: physical granule p = logical g ^ ((row>>1)&3); linear LDS dest,
  // inverse-permuted GLOBAL source (rule #21), same XOR on the read side.
  __shared__ _Float16 Ah[2][128 * 32];
  __shared__ _Float16 Al[2][128 * 32];
  __shared__ _Float16 Bh[2][128 * 32];
  __shared__ _Float16 Bl[2][128 * 32];

  int tid = threadIdx.x, lane = tid & 63, wid = tid >> 6;
  int wm = wid >> 1, wn = wid & 1;
  int bid = blockIdx.x;
  int wg = (bid & 7) * 1024 + (bid >> 3);   // XCD-bijective swizzle (8192 = 8*1024)
  int mblk = wg >> 4, nblk = wg & 15;
  int t0 = mblk * 128, c0 = nblk * 128;
  int col = lane & 15, kg = lane >> 4;

  float e2n[4];
#pragma unroll
  for (int n = 0; n < 4; ++n) e2n[n] = e2[c0 + wn * 64 + n * 16 + col];

  f32x4 acc[4][4] = {};

  auto stage = [&](int ck, int buf) {
    int kb = ck * 32;
#pragma unroll
    for (int q = 0; q < 2; ++q) {
      int j = wid * 2 + q;
      int row = j * 16 + (lane >> 2);
      int gl = (lane & 3) ^ ((row >> 1) & 3);
      size_t as = (size_t)(t0 + row) * DIMS + kb + gl * 8;
      size_t bs = (size_t)(c0 + row) * DIMS + kb + gl * 8;
      ld16(&Ah[buf][j * 512], &xh[as]);
      ld16(&Al[buf][j * 512], &xl[as]);
      ld16(&Bh[buf][j * 512], &eTh[bs]);
      ld16(&Bl[buf][j * 512], &eTl[bs]);
    }
  };

  stage(0, 0);
  __syncthreads();

  for (int c = 0; c < 8; ++c) {
    int buf = c & 1;
    if (c < 7) stage(c + 1, buf ^ 1);

    f16x8 ahf[4], alf[4], bhf[4], blf[4];
#pragma unroll
    for (int m = 0; m < 4; ++m) {
      int row = wm * 64 + m * 16 + col;
      int off = row * 32 + (kg ^ ((row >> 1) & 3)) * 8;
      ahf[m] = *(const f16x8*)&Ah[buf][off];
      alf[m] = *(const f16x8*)&Al[buf][off];
    }
#pragma unroll
    for (int n = 0; n < 4; ++n) {
      int row = wn * 64 + n * 16 + col;
      int off = row * 32 + (kg ^ ((row >> 1) & 3)) * 8;
      bhf[n] = *(const f16x8*)&Bh[buf][off];
      blf[n] = *(const f16x8*)&Bl[buf][off];
    }
#pragma unroll
    for (int m = 0; m < 4; ++m)
#pragma unroll
      for (int n = 0; n < 4; ++n) {
        acc[m][n] = __builtin_amdgcn_mfma_f32_16x16x32_f16(ahf[m], bhf[n], acc[m][n], 0, 0, 0);
        acc[m][n] = __builtin_amdgcn_mfma_f32_16x16x32_f16(ahf[m], blf[n], acc[m][n], 0, 0, 0);
        acc[m][n] = __builtin_amdgcn_mfma_f32_16x16x32_f16(alf[m], bhf[n], acc[m][n], 0, 0, 0);
      }
    __syncthreads();
  }

  // epilogue: s = e2 - 2*dot; sortable u64 key (low 32 = code -> lowest index on ties)
#pragma unroll
  for (int m = 0; m < 4; ++m)
#pragma unroll
    for (int r = 0; r < 4; ++r) {
      unsigned long long best = ~0ull;
#pragma unroll
      for (int n = 0; n < 4; ++n) {
        float s = e2n[n] - 2.0f * acc[m][n][r];
        unsigned u = __float_as_uint(s);
        u ^= (u & 0x80000000u) ? 0xFFFFFFFFu : 0x80000000u;
        unsigned long long key = ((unsigned long long)u << 32) |
                                 (unsigned)(c0 + wn * 64 + n * 16 + col);
        best = umin64(best, key);
      }
#pragma unroll
      for (int off = 1; off < 16; off <<= 1)
        best = umin64(best, __shfl_xor(best, off, 64));
      if (col == 0) {
        int token = t0 + wm * 64 + m * 16 + kg * 4 + r;
        atomicMin(&part[token], best);
      }
    }
}

// ---------- K2: extract indices ----------
__global__ void k_idx(const unsigned long long* __restrict__ part,
                      float* __restrict__ out, int* __restrict__ idxw) {
  int token = blockIdx.x * 256 + threadIdx.x;
  unsigned code = (unsigned)(part[token] & 0xFFFFFFFFull);
  out[IDXOFF + token] = (float)code;
  idxw[token] = (int)code;
}

// ---------- K3: gather codes, STE output, commitment loss (1 atomic / block) ----------
__global__ void k_gather(const float* __restrict__ x, const float* __restrict__ embedT,
                         const int* __restrict__ idxw, float* __restrict__ out) {
  int wid = threadIdx.x >> 6, lane = threadIdx.x & 63;
  int gw = blockIdx.x * 4 + wid;          // 8192 waves, 8 tokens each
  float s = 0.0f;
#pragma unroll
  for (int t = 0; t < 8; ++t) {
    int token = gw * 8 + t;
    int code = idxw[token];
    f32x4 q  = *(const f32x4*)&embedT[(size_t)code * DIMS + lane * 4];
    f32x4 xv = *(const f32x4*)&x[(size_t)token * DIMS + lane * 4];
    f32x4 d = q - xv;
    *(f32x4*)&out[(size_t)token * DIMS + lane * 4] = xv + d;
    s += d[0] * d[0] + d[1] * d[1] + d[2] * d[2] + d[3] * d[3];
  }
  for (int off = 32; off; off >>= 1) s += __shfl_xor(s, off, 64);
  __shared__ float red[4];
  if (lane == 0) red[wid] = s;
  __syncthreads();
  if (threadIdx.x == 0) {
    float tsum = (red[0] + red[1] + red[2] + red[3]) * (0.25f / 16777216.0f);
    atomicAdd(&out[LOSSOFF], tsum);
  }
}

extern "C" void kernel_launch(void* const* d_in, const int* in_sizes, int n_in,
                              void* d_out, int out_size, void* d_ws, size_t ws_size,
                              hipStream_t stream) {
  const float* x     = (const float*)d_in[0];
  const float* embed = (const float*)d_in[1];
  float* out = (float*)d_out;
  // x hi/lo fp16 planes live in the quantize region of d_out (exactly 64 MB),
  // overwritten by k_gather at the end.
  _Float16* xh = (_Float16*)d_out;
  _Float16* xl = (_Float16*)((char*)d_out + (32u << 20));
  char* w = (char*)d_ws;
  _Float16* eTh    = (_Float16*)w;                               // 1 MB
  _Float16* eTl    = (_Float16*)(w + (1u << 20));                // 1 MB
  float*    embedT = (float*)(w + (2u << 20));                   // 2 MB
  float*    e2     = (float*)(w + (4u << 20));                   // 8 KB
  unsigned long long* part = (unsigned long long*)(w + (4u << 20) + (1u << 15)); // 512 KB
  int*      idxw   = (int*)(w + (4u << 20) + (1u << 15) + (1u << 19));           // 256 KB

  hipLaunchKernelGGL(k_prep,   dim3(NCODE / 32, DIMS / 32), dim3(256), 0, stream, embed, embedT, eTh, eTl);
  hipLaunchKernelGGL(k_e2,     dim3(NCODE / 256),           dim3(256), 0, stream, embed, e2);
  hipLaunchKernelGGL(k_xsplit, dim3(2048),                  dim3(256), 0, stream, x, xh, xl);
  hipLaunchKernelGGL(k_init,   dim3(TOK / 256),             dim3(256), 0, stream, part, out);
  hipLaunchKernelGGL(k_score,  dim3(8192),                  dim3(256), 0, stream, xh, xl, eTh, eTl, e2, part);
  hipLaunchKernelGGL(k_idx,    dim3(TOK / 256),             dim3(256), 0, stream, part, out, idxw);
  hipLaunchKernelGGL(k_gather, dim3(2048),                  dim3(256), 0, stream, x, embedT, idxw, out);
}